// Round 9
// baseline (247.614 us; speedup 1.0000x reference)
//
#include <hip/hip_runtime.h>
#include <math.h>

#define EPSF 1e-12f
#define LOG2E 1.44269504f

// ---- DPP-based reductions (no DS pipe, no lane-addr calc) ----
// ctrl: 0xB1 quad_perm[1,0,3,2]=xor1, 0x4E quad_perm[2,3,0,1]=xor2,
//       0x141 row_half_mirror (^7 in 8), 0x140 row_mirror (^15 in 16).
template <int CTRL>
__device__ __forceinline__ float dppadd(float x) {
    union { float f; int i; } u, r;
    u.f = x;
    r.i = __builtin_amdgcn_update_dpp(0, u.i, CTRL, 0xF, 0xF, false);
    return x + r.f;
}
__device__ __forceinline__ float red16(float v) {
    v = dppadd<0xB1>(v); v = dppadd<0x4E>(v);
    v = dppadd<0x141>(v); v = dppadd<0x140>(v);
    return v;  // all 16 lanes hold the total
}
__device__ __forceinline__ float red8(float v) {
    v = dppadd<0xB1>(v); v = dppadd<0x4E>(v); v = dppadd<0x141>(v);
    return v;  // all 8 lanes hold the total
}

// tanh(x) = 1 - 2/(e^{2x}+1) with HW exp2/rcp (exact at +/-inf limits)
__device__ __forceinline__ float fast_tanh(float x) {
    float E = __builtin_amdgcn_exp2f(x * (2.0f * LOG2E));
    return 1.0f - 2.0f * __builtin_amdgcn_rcpf(E + 1.0f);
}

// 1/max(sqrt(x), 1e-12) == rsq(max(x, 1e-24)) (monotone transform, exact)
__device__ __forceinline__ float inv_norm(float x) {
    return __builtin_amdgcn_rsqf(fmaxf(x, 1e-24f));
}

__device__ __forceinline__ float leaky(float x) {
    return x > 0.0f ? x : 0.01f * x;
}

// ---- prep: per-node dot (first N*16 threads) + degree count (next E) ----
__global__ __launch_bounds__(256) void prep(
    const float* __restrict__ ent, const float* __restrict__ entT,
    float* __restrict__ dot, const int* __restrict__ dst,
    int* __restrict__ deg, int N16, int E) {
    int gid = blockIdx.x * 256 + threadIdx.x;
    if (gid < N16) {   // N16 is a multiple of 16, 16-lane rows never straddle
        int v = gid >> 4, lane = gid & 15;
        const float4 a = *(const float4*)(ent  + (size_t)v * 64 + lane * 4);
        const float4 b = *(const float4*)(entT + (size_t)v * 64 + lane * 4);
        float d = red16(a.x*b.x + a.y*b.y + a.z*b.z + a.w*b.w);
        if (lane == 0) dot[v] = d;
    } else {
        int e = gid - N16;
        if (e < E) atomicAdd(&deg[dst[e]], 1);
    }
}

// ---------------- CSR scan kernels ----------------

__global__ __launch_bounds__(256) void scan_reduce(
    const int* __restrict__ deg, int* __restrict__ part, int N) {
    __shared__ int sh[256];
    int t = threadIdx.x, i = blockIdx.x * 256 + t;
    sh[t] = (i < N) ? deg[i] : 0;
    __syncthreads();
    for (int off = 128; off > 0; off >>= 1) {
        if (t < off) sh[t] += sh[t + off];
        __syncthreads();
    }
    if (t == 0) part[blockIdx.x] = sh[0];
}

__global__ __launch_bounds__(1024) void scan_part(int* __restrict__ part, int nb) {
    __shared__ int sh[1024];
    int t = threadIdx.x;
    int x = (t < nb) ? part[t] : 0;
    sh[t] = x;
    __syncthreads();
    for (int off = 1; off < 1024; off <<= 1) {
        int y = (t >= off) ? sh[t - off] : 0;
        __syncthreads();
        sh[t] += y;
        __syncthreads();
    }
    if (t < nb) part[t] = sh[t] - x;  // exclusive
}

__global__ __launch_bounds__(256) void scan_write(
    int* __restrict__ rowptr, const int* __restrict__ part, int N) {
    __shared__ int sh[256];
    int t = threadIdx.x, i = blockIdx.x * 256 + t;
    int x = (i < N) ? rowptr[i] : 0;
    sh[t] = x;
    __syncthreads();
    for (int off = 1; off < 256; off <<= 1) {
        int y = (t >= off) ? sh[t - off] : 0;
        __syncthreads();
        sh[t] += y;
        __syncthreads();
    }
    if (i < N) rowptr[i] = part[blockIdx.x] + sh[t] - x;  // exclusive scan
}

// After this, rowptr[v] = end(v); start(v) = (v ? rowptr[v-1] : 0).
// Slot payload: int2{ src | ety<<20 , bitcast(dot[src]) }.
__global__ __launch_bounds__(256) void scatter_edges(
    const int* __restrict__ src, const int* __restrict__ dst,
    const int* __restrict__ ety, const float* __restrict__ dot,
    int* __restrict__ rowptr, int2* __restrict__ spk2, int E) {
    int e = blockIdx.x * 256 + threadIdx.x;
    if (e < E) {
        int sv = src[e];
        int slot = atomicAdd(&rowptr[dst[e]], 1);
        spk2[slot] = make_int2(sv | (ety[e] << 20), __float_as_int(dot[sv]));
    }
}

// ------------- fused layer-0: att + softmax + message + bi-layer GEMV -------
// ONE WAVE PER NODE: 4 groups of 16 lanes each take edge i*4+grp per
// iteration -> wave-uniform trip count (no masked-lane imbalance burn).
// GEMV: lanes 0-31 = W1 . a-vec, lanes 32-63 = W2 . b-vec, shfl_xor(32).
__global__ __launch_bounds__(256) void fused_l0(
    const int* __restrict__ rowptr, const int2* __restrict__ spk2,
    const float* __restrict__ ent, const float* __restrict__ dot,
    const float* __restrict__ relE, const float* __restrict__ relT,
    const float* __restrict__ W1, const float* __restrict__ b1,
    const float* __restrict__ W2, const float* __restrict__ b2,
    float* __restrict__ exatt, float* __restrict__ sinv,
    float* __restrict__ node1raw, float* __restrict__ out, int N) {
    __shared__ float  al[4][64];
    __shared__ float  bl[4][64];
    __shared__ float  rT[16][64];    // rel tables (16 rels x 64)
    __shared__ float  rE[16][64];
    __shared__ float4 WtA[16 * 32];  // W1^T: [dd][j] = W1[4dd..4dd+3][j]
    __shared__ float4 WtB[16 * 32];
    int t = threadIdx.x;

    {   // stage rel tables + transposed weights (256 threads)
        int r = t >> 4, c = (t & 15) * 4;
        *(float4*)&rT[r][c] = *(const float4*)(relT + r * 64 + c);
        *(float4*)&rE[r][c] = *(const float4*)(relE + r * 64 + c);
        int j = t & 31;
        for (int dd = t >> 5; dd < 16; dd += 8) {
            int d4 = dd * 4;
            WtA[dd * 32 + j] = make_float4(W1[(d4+0)*32 + j], W1[(d4+1)*32 + j],
                                           W1[(d4+2)*32 + j], W1[(d4+3)*32 + j]);
            WtB[dd * 32 + j] = make_float4(W2[(d4+0)*32 + j], W2[(d4+1)*32 + j],
                                           W2[(d4+2)*32 + j], W2[(d4+3)*32 + j]);
        }
    }
    __syncthreads();  // the only block barrier

    int wv = t >> 6;         // wave in block = node slot
    int l64 = t & 63;
    int grp = (t >> 4) & 3;  // edge group within wave
    int lane = t & 15;       // dim-quad within group
    int v = blockIdx.x * 4 + wv;
    if (v >= N) return;

    int s = v ? rowptr[v - 1] : 0;
    int epos = rowptr[v];

    const float4 he = *(const float4*)(ent + (size_t)v * 64 + lane * 4);
    float dh = dot[v];

    float4 macc = {0.f, 0.f, 0.f, 0.f};
    float sumex = 0.0f;

    for (int cb = s; cb < epos; cb += 64) {
        int cnt = epos - cb; if (cnt > 64) cnt = 64;
        int2 ms = spk2[cb + (l64 < cnt ? l64 : cnt - 1)];  // coalesced 8B
        int iters = (cnt + 3) >> 2;

        // prime group pipeline: edge (0*4 + grp)
        int cur = grp < cnt ? grp : cnt - 1;
        int pk = __shfl(ms.x, cur, 64);
        float sd = __int_as_float(__shfl(ms.y, cur, 64));
        float4 te = *(const float4*)(ent + (size_t)(pk & 0xFFFFF) * 64 + lane * 4);

        for (int i = 0; i < iters; ++i) {
            float4 ta = te;
            float  sa = sd;
            int pkc = pk;
            bool valid = (i * 4 + grp) < cnt;
            int sidx = cb + i * 4 + grp;

            if (i + 1 < iters) {  // prefetch next edge while computing this one
                int nxt = (i + 1) * 4 + grp; if (nxt >= cnt) nxt = cnt - 1;
                pk = __shfl(ms.x, nxt, 64);
                sd = __int_as_float(__shfl(ms.y, nxt, 64));
                te = *(const float4*)(ent + (size_t)(pk & 0xFFFFF) * 64 + lane * 4);
            }

            int rv = (pkc >> 20) & 15;
            const float4 rp = *(const float4*)&rT[rv][lane * 4];
            const float4 re = *(const float4*)&rE[rv][lane * 4];

            float4 mt, mh;
            mt.x = ta.x + sa * rp.x; mt.y = ta.y + sa * rp.y;
            mt.z = ta.z + sa * rp.z; mt.w = ta.w + sa * rp.w;
            mh.x = he.x + dh * rp.x; mh.y = he.y + dh * rp.y;
            mh.z = he.z + dh * rp.z; mh.w = he.w + dh * rp.w;

            float sst = red16(mt.x*mt.x + mt.y*mt.y + mt.z*mt.z + mt.w*mt.w);
            float ssh = red16(mh.x*mh.x + mh.y*mh.y + mh.z*mh.z + mh.w*mh.w);
            float it = inv_norm(sst), ih = inv_norm(ssh);

            float tx = fast_tanh(mh.x * ih + re.x);
            float ty = fast_tanh(mh.y * ih + re.y);
            float tz = fast_tanh(mh.z * ih + re.z);
            float tw = fast_tanh(mh.w * ih + re.w);

            float att = it * red16(mt.x*tx + mt.y*ty + mt.z*tz + mt.w*tw);
            // softmax shift-invariant; |att| <= 8 so exp is safe without max-sub
            float exR = __builtin_amdgcn_exp2f(att * LOG2E);
            float ex  = valid ? exR : 0.0f;
            if (lane == 0 && valid) exatt[sidx] = exR;  // raw; scaled by sinv later

            sumex += ex;
            macc.x += ex * ta.x; macc.y += ex * ta.y;
            macc.z += ex * ta.z; macc.w += ex * ta.w;
        }
    }

    // combine the 4 groups (width-64 xor by 16 and 32)
    sumex  += __shfl_xor(sumex,  16, 64); sumex  += __shfl_xor(sumex,  32, 64);
    macc.x += __shfl_xor(macc.x, 16, 64); macc.x += __shfl_xor(macc.x, 32, 64);
    macc.y += __shfl_xor(macc.y, 16, 64); macc.y += __shfl_xor(macc.y, 32, 64);
    macc.z += __shfl_xor(macc.z, 16, 64); macc.z += __shfl_xor(macc.z, 32, 64);
    macc.w += __shfl_xor(macc.w, 16, 64); macc.w += __shfl_xor(macc.w, 32, 64);

    float inv = 1.0f / fmaxf(sumex, EPSF);
    if (l64 == 0) sinv[v] = inv;
    macc.x *= inv; macc.y *= inv; macc.z *= inv; macc.w *= inv;

    if (l64 < 16) {
        // out cols 0..63 = ent_embed
        *(float4*)(out + (size_t)v * 112 + lane * 4) = he;
        float4 av, bv;
        av.x = he.x + macc.x; av.y = he.y + macc.y;
        av.z = he.z + macc.z; av.w = he.w + macc.w;
        bv.x = he.x * macc.x; bv.y = he.y * macc.y;
        bv.z = he.z * macc.z; bv.w = he.w * macc.w;
        *(float4*)&al[wv][lane * 4] = av;
        *(float4*)&bl[wv][lane * 4] = bv;
    }
    // no __syncthreads: writers and readers are the same wave (program order)

    int j = l64 & 31;
    bool second = l64 >= 32;
    const float*  sv_ = second ? bl[wv] : al[wv];
    const float4* Wt  = second ? WtB : WtA;
    float acc = second ? b2[j] : b1[j];
    #pragma unroll
    for (int dd = 0; dd < 16; ++dd) {
        float4 a4 = *(const float4*)&sv_[dd * 4];   // LDS broadcast read
        float4 w  = Wt[dd * 32 + j];                // coalesced b128
        acc += a4.x*w.x + a4.y*w.y + a4.z*w.z + a4.w*w.w;
    }
    float res = leaky(acc);
    res += __shfl_xor(res, 32, 64);  // leaky(W1.a) + leaky(W2.b)
    if (!second) node1raw[(size_t)v * 32 + j] = res;
}

// ------------- fused layer-1: message gather + bi-layer GEMV + norms --------
// 32 lanes per node (8 nodes / 256-block): 4 groups of 8 lanes, edge i*4+grp.
__global__ __launch_bounds__(256) void fused_l1(
    const int* __restrict__ rowptr, const int2* __restrict__ spk2,
    const float* __restrict__ exatt, const float* __restrict__ sinv,
    const float* __restrict__ node1raw,
    const float* __restrict__ W1, const float* __restrict__ b1,
    const float* __restrict__ W2, const float* __restrict__ b2,
    float* __restrict__ out, int N) {
    __shared__ float  A[8][32];
    __shared__ float  B[8][32];
    __shared__ float4 WtC[8 * 16];  // W1^T: [dd][j] = W1[4dd..4dd+3][j]
    __shared__ float4 WtD[8 * 16];
    int t = threadIdx.x;

    {   // stage transposed weights (first 128 threads W1, next 128 W2)
        int tt = t & 127;
        int j = tt & 15, dd = tt >> 4;  // dd 0..7
        int d4 = dd * 4;
        const float* W = (t < 128) ? W1 : W2;
        float4* Wt = (t < 128) ? WtC : WtD;
        Wt[dd * 16 + j] = make_float4(W[(d4+0)*16 + j], W[(d4+1)*16 + j],
                                      W[(d4+2)*16 + j], W[(d4+3)*16 + j]);
    }
    __syncthreads();

    int hv  = t >> 5;        // node slot in block (0..7)
    int l32 = t & 31;
    int grp = (t >> 3) & 3;  // edge group within node
    int lane = t & 7;        // dim-quad
    int v = blockIdx.x * 8 + hv;
    if (v >= N) return;

    int s = v ? rowptr[v - 1] : 0;
    int epos = rowptr[v];

    float4 n = *(const float4*)(node1raw + (size_t)v * 32 + lane * 4);
    float4 acc = {0.f, 0.f, 0.f, 0.f};

    for (int cb = s; cb < epos; cb += 32) {
        int cnt = epos - cb; if (cnt > 32) cnt = 32;
        int ld = cb + (l32 < cnt ? l32 : cnt - 1);
        int   mypk = spk2[ld].x;
        float myex = exatt[ld];
        int iters = (cnt + 3) >> 2;

        int cur = grp < cnt ? grp : cnt - 1;
        int pk = __shfl(mypk, cur, 32);
        float a0 = __shfl(myex, cur, 32);
        float4 x = *(const float4*)(node1raw + (size_t)(pk & 0xFFFFF) * 32 + lane * 4);

        for (int i = 0; i < iters; ++i) {
            float4 xa = x;
            float aa = a0;
            bool valid = (i * 4 + grp) < cnt;
            if (i + 1 < iters) {
                int nxt = (i + 1) * 4 + grp; if (nxt >= cnt) nxt = cnt - 1;
                pk = __shfl(mypk, nxt, 32);
                a0 = __shfl(myex, nxt, 32);
                x = *(const float4*)(node1raw + (size_t)(pk & 0xFFFFF) * 32 + lane * 4);
            }
            float w = valid ? aa : 0.0f;
            acc.x += w * xa.x; acc.y += w * xa.y;
            acc.z += w * xa.z; acc.w += w * xa.w;
        }
    }
    // combine the 4 groups (width-32 xor by 8 and 16)
    acc.x += __shfl_xor(acc.x, 8, 32); acc.x += __shfl_xor(acc.x, 16, 32);
    acc.y += __shfl_xor(acc.y, 8, 32); acc.y += __shfl_xor(acc.y, 16, 32);
    acc.z += __shfl_xor(acc.z, 8, 32); acc.z += __shfl_xor(acc.z, 16, 32);
    acc.w += __shfl_xor(acc.w, 8, 32); acc.w += __shfl_xor(acc.w, 16, 32);

    float inv = sinv[v];
    acc.x *= inv; acc.y *= inv; acc.z *= inv; acc.w *= inv;

    float ss = red8(n.x*n.x + n.y*n.y + n.z*n.z + n.w*n.w);
    float inv1 = inv_norm(ss);

    if (l32 < 8) {
        float4 nn = {n.x*inv1, n.y*inv1, n.z*inv1, n.w*inv1};
        *(float4*)(out + (size_t)v * 112 + 64 + lane * 4) = nn;
        float4 av = {n.x + acc.x, n.y + acc.y, n.z + acc.z, n.w + acc.w};
        float4 bv = {n.x * acc.x, n.y * acc.y, n.z * acc.z, n.w * acc.w};
        *(float4*)&A[hv][lane * 4] = av;
        *(float4*)&B[hv][lane * 4] = bv;
    }
    // no __syncthreads: writers and readers are the same wave (program order)

    int j = l32 & 15;
    bool second = l32 >= 16;
    const float*  sv_ = second ? B[hv] : A[hv];
    const float4* Wt  = second ? WtD : WtC;
    float a1 = second ? b2[j] : b1[j];
    #pragma unroll
    for (int dd = 0; dd < 8; ++dd) {
        float4 a4 = *(const float4*)&sv_[dd * 4];   // LDS broadcast read
        float4 w  = Wt[dd * 16 + j];
        a1 += a4.x*w.x + a4.y*w.y + a4.z*w.z + a4.w*w.w;
    }
    float res = leaky(a1);
    res += __shfl_xor(res, 16, 32);  // leaky(W1.a) + leaky(W2.b)
    if (!second) {
        float tot = res;
        float s2 = red16(tot * tot);
        float inv2 = inv_norm(s2);
        out[(size_t)v * 112 + 96 + j] = tot * inv2;  // cols 96..111
    }
}

extern "C" void kernel_launch(void* const* d_in, const int* in_sizes, int n_in,
                              void* d_out, int out_size, void* d_ws, size_t ws_size,
                              hipStream_t stream) {
    const int*   src  = (const int*)d_in[0];
    const int*   dst  = (const int*)d_in[1];
    const int*   ety  = (const int*)d_in[2];
    const float* ent  = (const float*)d_in[3];
    const float* entT = (const float*)d_in[4];
    const float* relE = (const float*)d_in[5];
    const float* relT = (const float*)d_in[6];
    const float* W1_0 = (const float*)d_in[7];
    const float* b1_0 = (const float*)d_in[8];
    const float* W2_0 = (const float*)d_in[9];
    const float* b2_0 = (const float*)d_in[10];
    const float* W1_1 = (const float*)d_in[11];
    const float* b1_1 = (const float*)d_in[12];
    const float* W2_1 = (const float*)d_in[13];
    const float* b2_1 = (const float*)d_in[14];
    float* out = (float*)d_out;

    const int E = in_sizes[0];
    const int N = in_sizes[3] / 64;
    const int nb = (N + 255) / 256;  // scan blocks (must be <= 1024)

    auto al256 = [](size_t x) { return (x + 255) & ~(size_t)255; };
    char* ws = (char*)d_ws;
    size_t offExatt = 0;
    size_t offS     = al256(offExatt + (size_t)E * 4);
    size_t offDot   = al256(offS + (size_t)N * 4);
    size_t offRow   = al256(offDot + (size_t)N * 4);
    size_t offSpk   = al256(offRow + (size_t)N * 4);
    size_t offPart  = al256(offSpk + (size_t)E * 8);
    size_t offN1    = al256(offPart + (size_t)nb * 4);
    float* exatt    = (float*)(ws + offExatt);
    float* sinv     = (float*)(ws + offS);
    float* dot      = (float*)(ws + offDot);
    int*   rowptr   = (int*)(ws + offRow);
    int2*  spk2     = (int2*)(ws + offSpk);
    int*   part     = (int*)(ws + offPart);
    float* node1raw = (float*)(ws + offN1);   // [N,32]

    // ---- CSR build + per-node dot ----
    hipMemsetAsync(rowptr, 0, (size_t)N * 4, stream);
    int N16 = N * 16;
    prep<<<(N16 + E + 255) / 256, 256, 0, stream>>>(ent, entT, dot, dst,
                                                    rowptr, N16, E);
    scan_reduce<<<nb, 256, 0, stream>>>(rowptr, part, N);
    scan_part<<<1, 1024, 0, stream>>>(part, nb);
    scan_write<<<nb, 256, 0, stream>>>(rowptr, part, N);
    int blkE = (E + 255) / 256;
    scatter_edges<<<blkE, 256, 0, stream>>>(src, dst, ety, dot, rowptr, spk2, E);

    // ---- fused layer 0: attention + softmax + message + node update ----
    fused_l0<<<(N + 3) / 4, 256, 0, stream>>>(
        rowptr, spk2, ent, dot, relE, relT,
        W1_0, b1_0, W2_0, b2_0, exatt, sinv, node1raw, out, N);

    // ---- fused layer 1: message + node update + norms ----
    fused_l1<<<(N + 7) / 8, 256, 0, stream>>>(
        rowptr, spk2, exatt, sinv, node1raw,
        W1_1, b1_1, W2_1, b2_1, out, N);
}

// Round 10
// 245.231 us; speedup vs baseline: 1.0097x; 1.0097x over previous
//
#include <hip/hip_runtime.h>
#include <math.h>

#define EPSF 1e-12f
#define LOG2E 1.44269504f

// ---- DPP-based reductions (no DS pipe, no lane-addr calc) ----
template <int CTRL>
__device__ __forceinline__ float dppadd(float x) {
    union { float f; int i; } u, r;
    u.f = x;
    r.i = __builtin_amdgcn_update_dpp(0, u.i, CTRL, 0xF, 0xF, false);
    return x + r.f;
}
__device__ __forceinline__ float red16(float v) {
    v = dppadd<0xB1>(v); v = dppadd<0x4E>(v);
    v = dppadd<0x141>(v); v = dppadd<0x140>(v);
    return v;  // all 16 lanes hold the total
}
__device__ __forceinline__ float red8(float v) {
    v = dppadd<0xB1>(v); v = dppadd<0x4E>(v); v = dppadd<0x141>(v);
    return v;  // all 8 lanes hold the total
}

// tanh(x) = 1 - 2/(e^{2x}+1) with HW exp2/rcp (exact at +/-inf limits)
__device__ __forceinline__ float fast_tanh(float x) {
    float E = __builtin_amdgcn_exp2f(x * (2.0f * LOG2E));
    return 1.0f - 2.0f * __builtin_amdgcn_rcpf(E + 1.0f);
}

// 1/max(sqrt(x), 1e-12) == rsq(max(x, 1e-24)) (monotone transform, exact)
__device__ __forceinline__ float inv_norm(float x) {
    return __builtin_amdgcn_rsqf(fmaxf(x, 1e-24f));
}

__device__ __forceinline__ float leaky(float x) {
    return x > 0.0f ? x : 0.01f * x;
}

// ---- prep: per-node dot (first N*16 threads) + degree count (next E) ----
__global__ __launch_bounds__(256) void prep(
    const float* __restrict__ ent, const float* __restrict__ entT,
    float* __restrict__ dot, const int* __restrict__ dst,
    int* __restrict__ deg, int N16, int E) {
    int gid = blockIdx.x * 256 + threadIdx.x;
    if (gid < N16) {   // N16 is a multiple of 16, 16-lane rows never straddle
        int v = gid >> 4, lane = gid & 15;
        const float4 a = *(const float4*)(ent  + (size_t)v * 64 + lane * 4);
        const float4 b = *(const float4*)(entT + (size_t)v * 64 + lane * 4);
        float d = red16(a.x*b.x + a.y*b.y + a.z*b.z + a.w*b.w);
        if (lane == 0) dot[v] = d;
    } else {
        int e = gid - N16;
        if (e < E) atomicAdd(&deg[dst[e]], 1);
    }
}

// ---------------- CSR scan kernels ----------------

__global__ __launch_bounds__(256) void scan_reduce(
    const int* __restrict__ deg, int* __restrict__ part, int N) {
    __shared__ int sh[256];
    int t = threadIdx.x, i = blockIdx.x * 256 + t;
    sh[t] = (i < N) ? deg[i] : 0;
    __syncthreads();
    for (int off = 128; off > 0; off >>= 1) {
        if (t < off) sh[t] += sh[t + off];
        __syncthreads();
    }
    if (t == 0) part[blockIdx.x] = sh[0];
}

__global__ __launch_bounds__(1024) void scan_part(int* __restrict__ part, int nb) {
    __shared__ int sh[1024];
    int t = threadIdx.x;
    int x = (t < nb) ? part[t] : 0;
    sh[t] = x;
    __syncthreads();
    for (int off = 1; off < 1024; off <<= 1) {
        int y = (t >= off) ? sh[t - off] : 0;
        __syncthreads();
        sh[t] += y;
        __syncthreads();
    }
    if (t < nb) part[t] = sh[t] - x;  // exclusive
}

__global__ __launch_bounds__(256) void scan_write(
    int* __restrict__ rowptr, const int* __restrict__ part, int N) {
    __shared__ int sh[256];
    int t = threadIdx.x, i = blockIdx.x * 256 + t;
    int x = (i < N) ? rowptr[i] : 0;
    sh[t] = x;
    __syncthreads();
    for (int off = 1; off < 256; off <<= 1) {
        int y = (t >= off) ? sh[t - off] : 0;
        __syncthreads();
        sh[t] += y;
        __syncthreads();
    }
    if (i < N) rowptr[i] = part[blockIdx.x] + sh[t] - x;  // exclusive scan
}

// After this, rowptr[v] = end(v); start(v) = (v ? rowptr[v-1] : 0).
// Slot payload: int2{ src | ety<<20 , bitcast(dot[src]) }.
__global__ __launch_bounds__(256) void scatter_edges(
    const int* __restrict__ src, const int* __restrict__ dst,
    const int* __restrict__ ety, const float* __restrict__ dot,
    int* __restrict__ rowptr, int2* __restrict__ spk2, int E) {
    int e = blockIdx.x * 256 + threadIdx.x;
    if (e < E) {
        int sv = src[e];
        int slot = atomicAdd(&rowptr[dst[e]], 1);
        spk2[slot] = make_int2(sv | (ety[e] << 20), __float_as_int(dot[sv]));
    }
}

// ------------- fused layer-0: att + softmax + message + bi-layer GEMV -------
// ONE WAVE PER NODE, DUAL-EDGE PIPELINE: 4 groups of 16 lanes; group g takes
// edges i*8+2g and i*8+2g+1 per iteration (2 independent chains = ILP 2),
// wave-uniform trip count ceil(deg/8). Next pair prefetched.
__global__ __launch_bounds__(256) void fused_l0(
    const int* __restrict__ rowptr, const int2* __restrict__ spk2,
    const float* __restrict__ ent, const float* __restrict__ dot,
    const float* __restrict__ relE, const float* __restrict__ relT,
    const float* __restrict__ W1, const float* __restrict__ b1,
    const float* __restrict__ W2, const float* __restrict__ b2,
    float* __restrict__ exatt, float* __restrict__ sinv,
    float* __restrict__ node1raw, float* __restrict__ out, int N) {
    __shared__ float  al[4][64];
    __shared__ float  bl[4][64];
    __shared__ float  rT[16][64];    // rel tables (16 rels x 64)
    __shared__ float  rE[16][64];
    __shared__ float4 WtA[16 * 32];  // W1^T: [dd][j] = W1[4dd..4dd+3][j]
    __shared__ float4 WtB[16 * 32];
    int t = threadIdx.x;

    {   // stage rel tables + transposed weights (256 threads)
        int r = t >> 4, c = (t & 15) * 4;
        *(float4*)&rT[r][c] = *(const float4*)(relT + r * 64 + c);
        *(float4*)&rE[r][c] = *(const float4*)(relE + r * 64 + c);
        int j = t & 31;
        for (int dd = t >> 5; dd < 16; dd += 8) {
            int d4 = dd * 4;
            WtA[dd * 32 + j] = make_float4(W1[(d4+0)*32 + j], W1[(d4+1)*32 + j],
                                           W1[(d4+2)*32 + j], W1[(d4+3)*32 + j]);
            WtB[dd * 32 + j] = make_float4(W2[(d4+0)*32 + j], W2[(d4+1)*32 + j],
                                           W2[(d4+2)*32 + j], W2[(d4+3)*32 + j]);
        }
    }
    __syncthreads();  // the only block barrier

    int wv = t >> 6;         // wave in block = node slot
    int l64 = t & 63;
    int grp = (t >> 4) & 3;  // edge group within wave
    int lane = t & 15;       // dim-quad within group
    int v = blockIdx.x * 4 + wv;
    if (v >= N) return;

    int s = v ? rowptr[v - 1] : 0;
    int epos = rowptr[v];

    const float4 he = *(const float4*)(ent + (size_t)v * 64 + lane * 4);
    float dh = dot[v];

    float4 macc = {0.f, 0.f, 0.f, 0.f};
    float sumex = 0.0f;

    for (int cb = s; cb < epos; cb += 64) {
        int cnt = epos - cb; if (cnt > 64) cnt = 64;
        int2 ms = spk2[cb + (l64 < cnt ? l64 : cnt - 1)];  // coalesced 8B
        int iters = (cnt + 7) >> 3;

        // prime the two pipes: edges 2g and 2g+1 (clamped; weight-zeroed)
        int ea0 = 2 * grp;            if (ea0 >= cnt) ea0 = cnt - 1;
        int eb0 = 2 * grp + 1;        if (eb0 >= cnt) eb0 = cnt - 1;
        int pkA = __shfl(ms.x, ea0, 64);
        int pkB = __shfl(ms.x, eb0, 64);
        float sdA = __int_as_float(__shfl(ms.y, ea0, 64));
        float sdB = __int_as_float(__shfl(ms.y, eb0, 64));
        float4 teA = *(const float4*)(ent + (size_t)(pkA & 0xFFFFF) * 64 + lane * 4);
        float4 teB = *(const float4*)(ent + (size_t)(pkB & 0xFFFFF) * 64 + lane * 4);

        for (int i = 0; i < iters; ++i) {
            float4 ta = teA, tb = teB;
            float  sa = sdA, sb = sdB;
            int pa = pkA, pb = pkB;
            int eA = i * 8 + 2 * grp, eB = eA + 1;
            bool va = eA < cnt, vb = eB < cnt;

            if (i + 1 < iters) {  // prefetch next pair while computing this one
                int nA = (i + 1) * 8 + 2 * grp; if (nA >= cnt) nA = cnt - 1;
                int nB = nA + 1;                if (nB >= cnt) nB = cnt - 1;
                pkA = __shfl(ms.x, nA, 64);
                pkB = __shfl(ms.x, nB, 64);
                sdA = __int_as_float(__shfl(ms.y, nA, 64));
                sdB = __int_as_float(__shfl(ms.y, nB, 64));
                teA = *(const float4*)(ent + (size_t)(pkA & 0xFFFFF) * 64 + lane * 4);
                teB = *(const float4*)(ent + (size_t)(pkB & 0xFFFFF) * 64 + lane * 4);
            }

            int rva = (pa >> 20) & 15;
            int rvb = (pb >> 20) & 15;
            const float4 rpa = *(const float4*)&rT[rva][lane * 4];
            const float4 rea = *(const float4*)&rE[rva][lane * 4];
            const float4 rpb = *(const float4*)&rT[rvb][lane * 4];
            const float4 reb = *(const float4*)&rE[rvb][lane * 4];

            float4 mta, mha, mtb, mhb;
            mta.x = ta.x + sa * rpa.x; mta.y = ta.y + sa * rpa.y;
            mta.z = ta.z + sa * rpa.z; mta.w = ta.w + sa * rpa.w;
            mha.x = he.x + dh * rpa.x; mha.y = he.y + dh * rpa.y;
            mha.z = he.z + dh * rpa.z; mha.w = he.w + dh * rpa.w;
            mtb.x = tb.x + sb * rpb.x; mtb.y = tb.y + sb * rpb.y;
            mtb.z = tb.z + sb * rpb.z; mtb.w = tb.w + sb * rpb.w;
            mhb.x = he.x + dh * rpb.x; mhb.y = he.y + dh * rpb.y;
            mhb.z = he.z + dh * rpb.z; mhb.w = he.w + dh * rpb.w;

            float ssta = red16(mta.x*mta.x + mta.y*mta.y + mta.z*mta.z + mta.w*mta.w);
            float ssha = red16(mha.x*mha.x + mha.y*mha.y + mha.z*mha.z + mha.w*mha.w);
            float sstb = red16(mtb.x*mtb.x + mtb.y*mtb.y + mtb.z*mtb.z + mtb.w*mtb.w);
            float sshb = red16(mhb.x*mhb.x + mhb.y*mhb.y + mhb.z*mhb.z + mhb.w*mhb.w);
            float ita = inv_norm(ssta), iha = inv_norm(ssha);
            float itb = inv_norm(sstb), ihb = inv_norm(sshb);

            float txa = fast_tanh(mha.x * iha + rea.x);
            float tya = fast_tanh(mha.y * iha + rea.y);
            float tza = fast_tanh(mha.z * iha + rea.z);
            float twa = fast_tanh(mha.w * iha + rea.w);
            float txb = fast_tanh(mhb.x * ihb + reb.x);
            float tyb = fast_tanh(mhb.y * ihb + reb.y);
            float tzb = fast_tanh(mhb.z * ihb + reb.z);
            float twb = fast_tanh(mhb.w * ihb + reb.w);

            float atta = ita * red16(mta.x*txa + mta.y*tya + mta.z*tza + mta.w*twa);
            float attb = itb * red16(mtb.x*txb + mtb.y*tyb + mtb.z*tzb + mtb.w*twb);

            // softmax shift-invariant; |att| <= 8 so exp is safe without max-sub
            float exaR = __builtin_amdgcn_exp2f(atta * LOG2E);
            float exbR = __builtin_amdgcn_exp2f(attb * LOG2E);
            float exa = va ? exaR : 0.0f;
            float exb = vb ? exbR : 0.0f;

            if (lane == 0) {
                if (va) exatt[cb + eA] = exaR;  // raw; consumers scale by sinv
                if (vb) exatt[cb + eB] = exbR;
            }
            sumex += exa + exb;
            macc.x += exa * ta.x + exb * tb.x;
            macc.y += exa * ta.y + exb * tb.y;
            macc.z += exa * ta.z + exb * tb.z;
            macc.w += exa * ta.w + exb * tb.w;
        }
    }

    // combine the 4 groups (width-64 xor by 16 and 32)
    sumex  += __shfl_xor(sumex,  16, 64); sumex  += __shfl_xor(sumex,  32, 64);
    macc.x += __shfl_xor(macc.x, 16, 64); macc.x += __shfl_xor(macc.x, 32, 64);
    macc.y += __shfl_xor(macc.y, 16, 64); macc.y += __shfl_xor(macc.y, 32, 64);
    macc.z += __shfl_xor(macc.z, 16, 64); macc.z += __shfl_xor(macc.z, 32, 64);
    macc.w += __shfl_xor(macc.w, 16, 64); macc.w += __shfl_xor(macc.w, 32, 64);

    float inv = 1.0f / fmaxf(sumex, EPSF);
    if (l64 == 0) sinv[v] = inv;
    macc.x *= inv; macc.y *= inv; macc.z *= inv; macc.w *= inv;

    if (l64 < 16) {
        // out cols 0..63 = ent_embed
        *(float4*)(out + (size_t)v * 112 + lane * 4) = he;
        float4 av, bv;
        av.x = he.x + macc.x; av.y = he.y + macc.y;
        av.z = he.z + macc.z; av.w = he.w + macc.w;
        bv.x = he.x * macc.x; bv.y = he.y * macc.y;
        bv.z = he.z * macc.z; bv.w = he.w * macc.w;
        *(float4*)&al[wv][lane * 4] = av;
        *(float4*)&bl[wv][lane * 4] = bv;
    }
    // no __syncthreads: writers and readers are the same wave (program order)

    int j = l64 & 31;
    bool second = l64 >= 32;
    const float*  sv_ = second ? bl[wv] : al[wv];
    const float4* Wt  = second ? WtB : WtA;
    float acc = second ? b2[j] : b1[j];
    #pragma unroll
    for (int dd = 0; dd < 16; ++dd) {
        float4 a4 = *(const float4*)&sv_[dd * 4];   // LDS broadcast read
        float4 w  = Wt[dd * 32 + j];                // coalesced b128
        acc += a4.x*w.x + a4.y*w.y + a4.z*w.z + a4.w*w.w;
    }
    float res = leaky(acc);
    res += __shfl_xor(res, 32, 64);  // leaky(W1.a) + leaky(W2.b)
    if (!second) node1raw[(size_t)v * 32 + j] = res;
}

// ------------- fused layer-1: message gather + bi-layer GEMV + norms --------
// 32 lanes per node (8 nodes / 256-block): 4 groups of 8 lanes, dual-edge
// pipeline (edges i*8+2g, i*8+2g+1), wave-uniform trips.
__global__ __launch_bounds__(256) void fused_l1(
    const int* __restrict__ rowptr, const int2* __restrict__ spk2,
    const float* __restrict__ exatt, const float* __restrict__ sinv,
    const float* __restrict__ node1raw,
    const float* __restrict__ W1, const float* __restrict__ b1,
    const float* __restrict__ W2, const float* __restrict__ b2,
    float* __restrict__ out, int N) {
    __shared__ float  A[8][32];
    __shared__ float  B[8][32];
    __shared__ float4 WtC[8 * 16];  // W1^T: [dd][j] = W1[4dd..4dd+3][j]
    __shared__ float4 WtD[8 * 16];
    int t = threadIdx.x;

    {   // stage transposed weights (first 128 threads W1, next 128 W2)
        int tt = t & 127;
        int j = tt & 15, dd = tt >> 4;  // dd 0..7
        int d4 = dd * 4;
        const float* W = (t < 128) ? W1 : W2;
        float4* Wt = (t < 128) ? WtC : WtD;
        Wt[dd * 16 + j] = make_float4(W[(d4+0)*16 + j], W[(d4+1)*16 + j],
                                      W[(d4+2)*16 + j], W[(d4+3)*16 + j]);
    }
    __syncthreads();

    int hv  = t >> 5;        // node slot in block (0..7)
    int l32 = t & 31;
    int grp = (t >> 3) & 3;  // edge group within node
    int lane = t & 7;        // dim-quad
    int v = blockIdx.x * 8 + hv;
    if (v >= N) return;

    int s = v ? rowptr[v - 1] : 0;
    int epos = rowptr[v];

    float4 n = *(const float4*)(node1raw + (size_t)v * 32 + lane * 4);
    float4 acc = {0.f, 0.f, 0.f, 0.f};

    for (int cb = s; cb < epos; cb += 32) {
        int cnt = epos - cb; if (cnt > 32) cnt = 32;
        int ld = cb + (l32 < cnt ? l32 : cnt - 1);
        int   mypk = spk2[ld].x;
        float myex = exatt[ld];
        int iters = (cnt + 7) >> 3;

        int ea0 = 2 * grp;     if (ea0 >= cnt) ea0 = cnt - 1;
        int eb0 = 2 * grp + 1; if (eb0 >= cnt) eb0 = cnt - 1;
        int pkA = __shfl(mypk, ea0, 32);
        int pkB = __shfl(mypk, eb0, 32);
        float aA = __shfl(myex, ea0, 32);
        float aB = __shfl(myex, eb0, 32);
        float4 xA = *(const float4*)(node1raw + (size_t)(pkA & 0xFFFFF) * 32 + lane * 4);
        float4 xB = *(const float4*)(node1raw + (size_t)(pkB & 0xFFFFF) * 32 + lane * 4);

        for (int i = 0; i < iters; ++i) {
            float4 xa = xA, xb = xB;
            float wa = aA, wb = aB;
            int eA = i * 8 + 2 * grp, eB = eA + 1;
            wa = (eA < cnt) ? wa : 0.0f;
            wb = (eB < cnt) ? wb : 0.0f;

            if (i + 1 < iters) {
                int nA = (i + 1) * 8 + 2 * grp; if (nA >= cnt) nA = cnt - 1;
                int nB = nA + 1;                if (nB >= cnt) nB = cnt - 1;
                pkA = __shfl(mypk, nA, 32);
                pkB = __shfl(mypk, nB, 32);
                aA = __shfl(myex, nA, 32);
                aB = __shfl(myex, nB, 32);
                xA = *(const float4*)(node1raw + (size_t)(pkA & 0xFFFFF) * 32 + lane * 4);
                xB = *(const float4*)(node1raw + (size_t)(pkB & 0xFFFFF) * 32 + lane * 4);
            }
            acc.x += wa * xa.x + wb * xb.x;
            acc.y += wa * xa.y + wb * xb.y;
            acc.z += wa * xa.z + wb * xb.z;
            acc.w += wa * xa.w + wb * xb.w;
        }
    }
    // combine the 4 groups (width-32 xor by 8 and 16)
    acc.x += __shfl_xor(acc.x, 8, 32); acc.x += __shfl_xor(acc.x, 16, 32);
    acc.y += __shfl_xor(acc.y, 8, 32); acc.y += __shfl_xor(acc.y, 16, 32);
    acc.z += __shfl_xor(acc.z, 8, 32); acc.z += __shfl_xor(acc.z, 16, 32);
    acc.w += __shfl_xor(acc.w, 8, 32); acc.w += __shfl_xor(acc.w, 16, 32);

    float inv = sinv[v];
    acc.x *= inv; acc.y *= inv; acc.z *= inv; acc.w *= inv;

    float ss = red8(n.x*n.x + n.y*n.y + n.z*n.z + n.w*n.w);
    float inv1 = inv_norm(ss);

    if (l32 < 8) {
        float4 nn = {n.x*inv1, n.y*inv1, n.z*inv1, n.w*inv1};
        *(float4*)(out + (size_t)v * 112 + 64 + lane * 4) = nn;
        float4 av = {n.x + acc.x, n.y + acc.y, n.z + acc.z, n.w + acc.w};
        float4 bv = {n.x * acc.x, n.y * acc.y, n.z * acc.z, n.w * acc.w};
        *(float4*)&A[hv][lane * 4] = av;
        *(float4*)&B[hv][lane * 4] = bv;
    }
    // no __syncthreads: writers and readers are the same wave (program order)

    int j = l32 & 15;
    bool second = l32 >= 16;
    const float*  sv_ = second ? B[hv] : A[hv];
    const float4* Wt  = second ? WtD : WtC;
    float a1 = second ? b2[j] : b1[j];
    #pragma unroll
    for (int dd = 0; dd < 8; ++dd) {
        float4 a4 = *(const float4*)&sv_[dd * 4];   // LDS broadcast read
        float4 w  = Wt[dd * 16 + j];
        a1 += a4.x*w.x + a4.y*w.y + a4.z*w.z + a4.w*w.w;
    }
    float res = leaky(a1);
    res += __shfl_xor(res, 16, 32);  // leaky(W1.a) + leaky(W2.b)
    if (!second) {
        float tot = res;
        float s2 = red16(tot * tot);
        float inv2 = inv_norm(s2);
        out[(size_t)v * 112 + 96 + j] = tot * inv2;  // cols 96..111
    }
}

extern "C" void kernel_launch(void* const* d_in, const int* in_sizes, int n_in,
                              void* d_out, int out_size, void* d_ws, size_t ws_size,
                              hipStream_t stream) {
    const int*   src  = (const int*)d_in[0];
    const int*   dst  = (const int*)d_in[1];
    const int*   ety  = (const int*)d_in[2];
    const float* ent  = (const float*)d_in[3];
    const float* entT = (const float*)d_in[4];
    const float* relE = (const float*)d_in[5];
    const float* relT = (const float*)d_in[6];
    const float* W1_0 = (const float*)d_in[7];
    const float* b1_0 = (const float*)d_in[8];
    const float* W2_0 = (const float*)d_in[9];
    const float* b2_0 = (const float*)d_in[10];
    const float* W1_1 = (const float*)d_in[11];
    const float* b1_1 = (const float*)d_in[12];
    const float* W2_1 = (const float*)d_in[13];
    const float* b2_1 = (const float*)d_in[14];
    float* out = (float*)d_out;

    const int E = in_sizes[0];
    const int N = in_sizes[3] / 64;
    const int nb = (N + 255) / 256;  // scan blocks (must be <= 1024)

    auto al256 = [](size_t x) { return (x + 255) & ~(size_t)255; };
    char* ws = (char*)d_ws;
    size_t offExatt = 0;
    size_t offS     = al256(offExatt + (size_t)E * 4);
    size_t offDot   = al256(offS + (size_t)N * 4);
    size_t offRow   = al256(offDot + (size_t)N * 4);
    size_t offSpk   = al256(offRow + (size_t)N * 4);
    size_t offPart  = al256(offSpk + (size_t)E * 8);
    size_t offN1    = al256(offPart + (size_t)nb * 4);
    float* exatt    = (float*)(ws + offExatt);
    float* sinv     = (float*)(ws + offS);
    float* dot      = (float*)(ws + offDot);
    int*   rowptr   = (int*)(ws + offRow);
    int2*  spk2     = (int2*)(ws + offSpk);
    int*   part     = (int*)(ws + offPart);
    float* node1raw = (float*)(ws + offN1);   // [N,32]

    // ---- CSR build + per-node dot ----
    hipMemsetAsync(rowptr, 0, (size_t)N * 4, stream);
    int N16 = N * 16;
    prep<<<(N16 + E + 255) / 256, 256, 0, stream>>>(ent, entT, dot, dst,
                                                    rowptr, N16, E);
    scan_reduce<<<nb, 256, 0, stream>>>(rowptr, part, N);
    scan_part<<<1, 1024, 0, stream>>>(part, nb);
    scan_write<<<nb, 256, 0, stream>>>(rowptr, part, N);
    int blkE = (E + 255) / 256;
    scatter_edges<<<blkE, 256, 0, stream>>>(src, dst, ety, dot, rowptr, spk2, E);

    // ---- fused layer 0: attention + softmax + message + node update ----
    fused_l0<<<(N + 3) / 4, 256, 0, stream>>>(
        rowptr, spk2, ent, dot, relE, relT,
        W1_0, b1_0, W2_0, b2_0, exatt, sinv, node1raw, out, N);

    // ---- fused layer 1: message + node update + norms ----
    fused_l1<<<(N + 7) / 8, 256, 0, stream>>>(
        rowptr, spk2, exatt, sinv, node1raw,
        W1_1, b1_1, W2_1, b2_1, out, N);
}

// Round 11
// 242.856 us; speedup vs baseline: 1.0196x; 1.0098x over previous
//
#include <hip/hip_runtime.h>
#include <math.h>

#define EPSF 1e-12f
#define LOG2E 1.44269504f

// ---- DPP-based reductions (no DS pipe, no lane-addr calc) ----
template <int CTRL>
__device__ __forceinline__ float dppadd(float x) {
    union { float f; int i; } u, r;
    u.f = x;
    r.i = __builtin_amdgcn_update_dpp(0, u.i, CTRL, 0xF, 0xF, false);
    return x + r.f;
}
__device__ __forceinline__ float red16(float v) {
    v = dppadd<0xB1>(v); v = dppadd<0x4E>(v);
    v = dppadd<0x141>(v); v = dppadd<0x140>(v);
    return v;  // all 16 lanes hold the total
}
__device__ __forceinline__ float red8(float v) {
    v = dppadd<0xB1>(v); v = dppadd<0x4E>(v); v = dppadd<0x141>(v);
    return v;  // all 8 lanes hold the total
}
__device__ __forceinline__ float xor8add(float v) {  // combine 8-halves in 16
    return dppadd<0x128>(v);
}

// tanh(x) = 1 - 2/(e^{2x}+1) with HW exp2/rcp (exact at +/-inf limits)
__device__ __forceinline__ float fast_tanh(float x) {
    float E = __builtin_amdgcn_exp2f(x * (2.0f * LOG2E));
    return 1.0f - 2.0f * __builtin_amdgcn_rcpf(E + 1.0f);
}

// 1/max(sqrt(x), 1e-12) == rsq(max(x, 1e-24)) (monotone transform, exact)
__device__ __forceinline__ float inv_norm(float x) {
    return __builtin_amdgcn_rsqf(fmaxf(x, 1e-24f));
}

__device__ __forceinline__ float leaky(float x) {
    return x > 0.0f ? x : 0.01f * x;
}

// ---- prep: per-node dot (first N*16 threads) + degree count (next E)
//      + transposed-weight build (last 1280 items) ----
__global__ __launch_bounds__(256) void prep(
    const float* __restrict__ ent, const float* __restrict__ entT,
    float* __restrict__ dot, const int* __restrict__ dst,
    int* __restrict__ deg, int N16, int E,
    const float* __restrict__ W10, const float* __restrict__ W20,
    const float* __restrict__ W11, const float* __restrict__ W21,
    float4* __restrict__ wt) {
    int gid = blockIdx.x * 256 + threadIdx.x;
    if (gid < N16) {   // N16 is a multiple of 16, 16-lane rows never straddle
        int v = gid >> 4, lane = gid & 15;
        const float4 a = *(const float4*)(ent  + (size_t)v * 64 + lane * 4);
        const float4 b = *(const float4*)(entT + (size_t)v * 64 + lane * 4);
        float d = red16(a.x*b.x + a.y*b.y + a.z*b.z + a.w*b.w);
        if (lane == 0) dot[v] = d;
    } else if (gid < N16 + E) {
        int e = gid - N16;
        atomicAdd(&deg[dst[e]], 1);
    } else {
        int w = gid - N16 - E;  // 0..1279: build W^T float4 blocks
        if (w < 512) {
            int dd = w >> 5, j = w & 31, d4 = dd * 4;
            wt[w] = make_float4(W10[(d4+0)*32+j], W10[(d4+1)*32+j],
                                W10[(d4+2)*32+j], W10[(d4+3)*32+j]);
        } else if (w < 1024) {
            int u = w - 512, dd = u >> 5, j = u & 31, d4 = dd * 4;
            wt[w] = make_float4(W20[(d4+0)*32+j], W20[(d4+1)*32+j],
                                W20[(d4+2)*32+j], W20[(d4+3)*32+j]);
        } else if (w < 1152) {
            int u = w - 1024, dd = u >> 4, j = u & 15, d4 = dd * 4;
            wt[w] = make_float4(W11[(d4+0)*16+j], W11[(d4+1)*16+j],
                                W11[(d4+2)*16+j], W11[(d4+3)*16+j]);
        } else if (w < 1280) {
            int u = w - 1152, dd = u >> 4, j = u & 15, d4 = dd * 4;
            wt[w] = make_float4(W21[(d4+0)*16+j], W21[(d4+1)*16+j],
                                W21[(d4+2)*16+j], W21[(d4+3)*16+j]);
        }
    }
}

// ---------------- CSR scan kernels ----------------

__global__ __launch_bounds__(256) void scan_reduce(
    const int* __restrict__ deg, int* __restrict__ part, int N) {
    __shared__ int sh[256];
    int t = threadIdx.x, i = blockIdx.x * 256 + t;
    sh[t] = (i < N) ? deg[i] : 0;
    __syncthreads();
    for (int off = 128; off > 0; off >>= 1) {
        if (t < off) sh[t] += sh[t + off];
        __syncthreads();
    }
    if (t == 0) part[blockIdx.x] = sh[0];
}

__global__ __launch_bounds__(1024) void scan_part(int* __restrict__ part, int nb) {
    __shared__ int sh[1024];
    int t = threadIdx.x;
    int x = (t < nb) ? part[t] : 0;
    sh[t] = x;
    __syncthreads();
    for (int off = 1; off < 1024; off <<= 1) {
        int y = (t >= off) ? sh[t - off] : 0;
        __syncthreads();
        sh[t] += y;
        __syncthreads();
    }
    if (t < nb) part[t] = sh[t] - x;  // exclusive
}

__global__ __launch_bounds__(256) void scan_write(
    int* __restrict__ rowptr, const int* __restrict__ part, int N) {
    __shared__ int sh[256];
    int t = threadIdx.x, i = blockIdx.x * 256 + t;
    int x = (i < N) ? rowptr[i] : 0;
    sh[t] = x;
    __syncthreads();
    for (int off = 1; off < 256; off <<= 1) {
        int y = (t >= off) ? sh[t - off] : 0;
        __syncthreads();
        sh[t] += y;
        __syncthreads();
    }
    if (i < N) rowptr[i] = part[blockIdx.x] + sh[t] - x;  // exclusive scan
}

// After this, rowptr[v] = end(v); start(v) = (v ? rowptr[v-1] : 0).
// Slot payload: int2{ src | ety<<20 , bitcast(dot[src]) }.
__global__ __launch_bounds__(256) void scatter_edges(
    const int* __restrict__ src, const int* __restrict__ dst,
    const int* __restrict__ ety, const float* __restrict__ dot,
    int* __restrict__ rowptr, int2* __restrict__ spk2, int E) {
    int e = blockIdx.x * 256 + threadIdx.x;
    if (e < E) {
        int sv = src[e];
        int slot = atomicAdd(&rowptr[dst[e]], 1);
        spk2[slot] = make_int2(sv | (ety[e] << 20), __float_as_int(dot[sv]));
    }
}

// ------------- fused layer-0: att + softmax + message + bi-layer GEMV -------
// 32 lanes per dst node (8 nodes / 256-thread block): two 16-lane halves each
// walk half the node's edge list with a dual-edge pipeline + next-pair
// prefetch. Grid-stride over nodes; staging amortized across ~100 nodes.
__global__ __launch_bounds__(256) void fused_l0(
    const int* __restrict__ rowptr, const int2* __restrict__ spk2,
    const float* __restrict__ ent, const float* __restrict__ dot,
    const float* __restrict__ relE, const float* __restrict__ relT,
    const float4* __restrict__ wt,
    const float* __restrict__ b1, const float* __restrict__ b2,
    float* __restrict__ exatt, float* __restrict__ sinv,
    float* __restrict__ node1raw, float* __restrict__ out, int N) {
    __shared__ float  al[8][64];
    __shared__ float  bl[8][64];
    __shared__ float  rT[16][64];    // rel tables (16 rels x 64)
    __shared__ float  rE[16][64];
    __shared__ float4 WtA[512];      // W1^T (pre-transposed in prep)
    __shared__ float4 WtB[512];
    __shared__ float  bias1[32], bias2[32];
    int t = threadIdx.x;

    {   // stage rel tables + weights (pure float4 copies) + biases
        int r = t >> 4, c = (t & 15) * 4;
        *(float4*)&rT[r][c] = *(const float4*)(relT + r * 64 + c);
        *(float4*)&rE[r][c] = *(const float4*)(relE + r * 64 + c);
        WtA[t]       = wt[t];
        WtA[t + 256] = wt[t + 256];
        WtB[t]       = wt[512 + t];
        WtB[t + 256] = wt[768 + t];
        if (t < 32) { bias1[t] = b1[t]; bias2[t] = b2[t]; }
    }
    __syncthreads();  // the only block barrier

    int nv = t >> 5, half = (t >> 4) & 1, lane = t & 15;

    for (int v = blockIdx.x * 8 + nv; v < N; v += gridDim.x * 8) {
        int s = v ? rowptr[v - 1] : 0;
        int epos = rowptr[v];
        int deg = epos - s;
        int mid = s + ((deg + 1) >> 1);
        int hs   = half ? mid  : s;
        int hend = half ? epos : mid;

        const float4 he = *(const float4*)(ent + (size_t)v * 64 + lane * 4);
        float dh = dot[v];

        float4 macc = {0.f, 0.f, 0.f, 0.f};
        float sumex = 0.0f;

        for (int base = hs; base < hend; base += 16) {
            int rem = hend - base;
            int cnt = rem < 16 ? rem : 16;
            int2 ms = spk2[base + (lane < rem ? lane : rem - 1)];  // 8B coalesced
            float myex = 0.0f;

            int pk0 = __shfl(ms.x, 0, 16);
            int pk1 = __shfl(ms.x, cnt > 1 ? 1 : 0, 16);
            float sd0 = __int_as_float(__shfl(ms.y, 0, 16));
            float sd1 = __int_as_float(__shfl(ms.y, cnt > 1 ? 1 : 0, 16));
            float4 te0 = *(const float4*)(ent + (size_t)(pk0 & 0xFFFFF) * 64 + lane * 4);
            float4 te1 = *(const float4*)(ent + (size_t)(pk1 & 0xFFFFF) * 64 + lane * 4);

            for (int k = 0; k < cnt; k += 2) {
                float4 ta = te0, tb = te1;
                float  sa = sd0, sb = sd1;
                int rva = (pk0 >> 20) & 15;
                int rvb = (pk1 >> 20) & 15;
                bool hasb = (k + 1) < cnt;

                if (k + 2 < cnt) {  // prefetch next pair while computing
                    int i2 = k + 2, i3 = (k + 3 < cnt) ? (k + 3) : (k + 2);
                    pk0 = __shfl(ms.x, i2, 16);
                    pk1 = __shfl(ms.x, i3, 16);
                    sd0 = __int_as_float(__shfl(ms.y, i2, 16));
                    sd1 = __int_as_float(__shfl(ms.y, i3, 16));
                    te0 = *(const float4*)(ent + (size_t)(pk0 & 0xFFFFF) * 64 + lane * 4);
                    te1 = *(const float4*)(ent + (size_t)(pk1 & 0xFFFFF) * 64 + lane * 4);
                }

                const float4 rpa = *(const float4*)&rT[rva][lane * 4];
                const float4 rea = *(const float4*)&rE[rva][lane * 4];
                const float4 rpb = *(const float4*)&rT[rvb][lane * 4];
                const float4 reb = *(const float4*)&rE[rvb][lane * 4];

                float4 mta, mha, mtb, mhb;
                mta.x = ta.x + sa * rpa.x; mta.y = ta.y + sa * rpa.y;
                mta.z = ta.z + sa * rpa.z; mta.w = ta.w + sa * rpa.w;
                mha.x = he.x + dh * rpa.x; mha.y = he.y + dh * rpa.y;
                mha.z = he.z + dh * rpa.z; mha.w = he.w + dh * rpa.w;
                mtb.x = tb.x + sb * rpb.x; mtb.y = tb.y + sb * rpb.y;
                mtb.z = tb.z + sb * rpb.z; mtb.w = tb.w + sb * rpb.w;
                mhb.x = he.x + dh * rpb.x; mhb.y = he.y + dh * rpb.y;
                mhb.z = he.z + dh * rpb.z; mhb.w = he.w + dh * rpb.w;

                float ssta = red16(mta.x*mta.x + mta.y*mta.y + mta.z*mta.z + mta.w*mta.w);
                float ssha = red16(mha.x*mha.x + mha.y*mha.y + mha.z*mha.z + mha.w*mha.w);
                float sstb = red16(mtb.x*mtb.x + mtb.y*mtb.y + mtb.z*mtb.z + mtb.w*mtb.w);
                float sshb = red16(mhb.x*mhb.x + mhb.y*mhb.y + mhb.z*mhb.z + mhb.w*mhb.w);
                float ita = inv_norm(ssta), iha = inv_norm(ssha);
                float itb = inv_norm(sstb), ihb = inv_norm(sshb);

                float txa = fast_tanh(mha.x * iha + rea.x);
                float tya = fast_tanh(mha.y * iha + rea.y);
                float tza = fast_tanh(mha.z * iha + rea.z);
                float twa = fast_tanh(mha.w * iha + rea.w);
                float txb = fast_tanh(mhb.x * ihb + reb.x);
                float tyb = fast_tanh(mhb.y * ihb + reb.y);
                float tzb = fast_tanh(mhb.z * ihb + reb.z);
                float twb = fast_tanh(mhb.w * ihb + reb.w);

                float atta = ita * red16(mta.x*txa + mta.y*tya + mta.z*tza + mta.w*twa);
                float attb = itb * red16(mtb.x*txb + mtb.y*tyb + mtb.z*tzb + mtb.w*twb);

                // softmax shift-invariant; |att| <= 8 so exp safe without max-sub
                float exa  = __builtin_amdgcn_exp2f(atta * LOG2E);
                float exbR = __builtin_amdgcn_exp2f(attb * LOG2E);
                float exb  = hasb ? exbR : 0.0f;

                // lane k captures its edge's raw ex; stored coalesced per chunk
                myex = (lane == k) ? exa : myex;
                myex = (lane == k + 1) ? exbR : myex;

                sumex += exa + exb;
                macc.x += exa * ta.x + exb * tb.x;
                macc.y += exa * ta.y + exb * tb.y;
                macc.z += exa * ta.z + exb * tb.z;
                macc.w += exa * ta.w + exb * tb.w;
            }
            if (lane < cnt) exatt[base + lane] = myex;
        }

        // combine the two halves of this node (width-32 xor-by-16)
        sumex  += __shfl_xor(sumex,  16, 32);
        macc.x += __shfl_xor(macc.x, 16, 32);
        macc.y += __shfl_xor(macc.y, 16, 32);
        macc.z += __shfl_xor(macc.z, 16, 32);
        macc.w += __shfl_xor(macc.w, 16, 32);

        float inv = 1.0f / fmaxf(sumex, EPSF);
        if ((t & 31) == 0) sinv[v] = inv;
        macc.x *= inv; macc.y *= inv; macc.z *= inv; macc.w *= inv;

        if (!half) {
            // out cols 0..63 = ent_embed
            *(float4*)(out + (size_t)v * 112 + lane * 4) = he;
            float4 av, bv;
            av.x = he.x + macc.x; av.y = he.y + macc.y;
            av.z = he.z + macc.z; av.w = he.w + macc.w;
            bv.x = he.x * macc.x; bv.y = he.y * macc.y;
            bv.z = he.z * macc.z; bv.w = he.w * macc.w;
            *(float4*)&al[nv][lane * 4] = av;
            *(float4*)&bl[nv][lane * 4] = bv;
        }
        // no __syncthreads: writers and readers are the same wave

        int j = t & 31;
        float acc1 = bias1[j], acc2 = bias2[j];
        #pragma unroll
        for (int dd = 0; dd < 16; ++dd) {
            float4 a4 = *(const float4*)&al[nv][dd * 4];   // LDS broadcast
            float4 b4 = *(const float4*)&bl[nv][dd * 4];
            float4 wa = WtA[dd * 32 + j];                  // coalesced b128
            float4 wb = WtB[dd * 32 + j];
            acc1 += a4.x*wa.x + a4.y*wa.y + a4.z*wa.z + a4.w*wa.w;
            acc2 += b4.x*wb.x + b4.y*wb.y + b4.z*wb.z + b4.w*wb.w;
        }
        node1raw[(size_t)v * 32 + j] = leaky(acc1) + leaky(acc2);
    }
}

// ------------- fused layer-1: message gather + bi-layer GEMV + norms --------
// 16 lanes per node (16 nodes / block): two 8-lane halves, dual-edge pipeline,
// grid-stride over nodes.
__global__ __launch_bounds__(256) void fused_l1(
    const int* __restrict__ rowptr, const int2* __restrict__ spk2,
    const float* __restrict__ exatt, const float* __restrict__ sinv,
    const float* __restrict__ node1raw, const float4* __restrict__ wt,
    const float* __restrict__ b1, const float* __restrict__ b2,
    float* __restrict__ out, int N) {
    __shared__ float  A[16][32];
    __shared__ float  B[16][32];
    __shared__ float4 WtC[128];  // W1^T (pre-transposed in prep)
    __shared__ float4 WtD[128];
    __shared__ float  bias1[16], bias2[16];
    int t = threadIdx.x;

    {   // stage weights (pure float4 copies) + biases
        if (t < 128) WtC[t] = wt[1024 + t];
        else if (t < 256) WtD[t - 128] = wt[1024 + t];
        if (t < 16) { bias1[t] = b1[t]; bias2[t] = b2[t]; }
    }
    __syncthreads();

    int nv = t >> 4, half = (t >> 3) & 1, lane = t & 7;

    for (int v = blockIdx.x * 16 + nv; v < N; v += gridDim.x * 16) {
        int s = v ? rowptr[v - 1] : 0;
        int epos = rowptr[v];
        int deg = epos - s;
        int mid = s + ((deg + 1) >> 1);
        int hs   = half ? mid  : s;
        int hend = half ? epos : mid;

        float4 n = *(const float4*)(node1raw + (size_t)v * 32 + lane * 4);
        float4 acc = {0.f, 0.f, 0.f, 0.f};

        for (int base = hs; base < hend; base += 8) {
            int rem = hend - base;
            int cnt = rem < 8 ? rem : 8;
            int idx = base + (lane < rem ? lane : rem - 1);
            int   mypk = spk2[idx].x;
            float myex = exatt[idx];

            int pk0 = __shfl(mypk, 0, 8);
            int pk1 = __shfl(mypk, cnt > 1 ? 1 : 0, 8);
            float4 x0 = *(const float4*)(node1raw + (size_t)(pk0 & 0xFFFFF) * 32 + lane * 4);
            float4 x1 = *(const float4*)(node1raw + (size_t)(pk1 & 0xFFFFF) * 32 + lane * 4);

            for (int k = 0; k < cnt; k += 2) {
                float4 xa = x0, xb = x1;
                float aa = __shfl(myex, k, 8);
                float ab = __shfl(myex, (k + 1 < cnt) ? (k + 1) : k, 8);
                if (!((k + 1) < cnt)) ab = 0.0f;

                if (k + 2 < cnt) {
                    pk0 = __shfl(mypk, k + 2, 8);
                    pk1 = __shfl(mypk, (k + 3 < cnt) ? (k + 3) : (k + 2), 8);
                    x0 = *(const float4*)(node1raw + (size_t)(pk0 & 0xFFFFF) * 32 + lane * 4);
                    x1 = *(const float4*)(node1raw + (size_t)(pk1 & 0xFFFFF) * 32 + lane * 4);
                }
                acc.x += aa * xa.x + ab * xb.x;
                acc.y += aa * xa.y + ab * xb.y;
                acc.z += aa * xa.z + ab * xb.z;
                acc.w += aa * xa.w + ab * xb.w;
            }
        }
        // combine halves (lane^8 within 16, via DPP row_ror:8)
        acc.x = xor8add(acc.x);
        acc.y = xor8add(acc.y);
        acc.z = xor8add(acc.z);
        acc.w = xor8add(acc.w);

        float inv = sinv[v];
        acc.x *= inv; acc.y *= inv; acc.z *= inv; acc.w *= inv;

        float ss = red8(n.x*n.x + n.y*n.y + n.z*n.z + n.w*n.w);
        float inv1 = inv_norm(ss);

        if (!half) {
            float4 nn = {n.x*inv1, n.y*inv1, n.z*inv1, n.w*inv1};
            *(float4*)(out + (size_t)v * 112 + 64 + lane * 4) = nn;
            float4 av = {n.x + acc.x, n.y + acc.y, n.z + acc.z, n.w + acc.w};
            float4 bv = {n.x * acc.x, n.y * acc.y, n.z * acc.z, n.w * acc.w};
            *(float4*)&A[nv][lane * 4] = av;
            *(float4*)&B[nv][lane * 4] = bv;
        }
        // no __syncthreads: writers and readers are the same wave

        int j = t & 15;
        float a1 = bias1[j], a2 = bias2[j];
        #pragma unroll
        for (int dd = 0; dd < 8; ++dd) {
            float4 a4 = *(const float4*)&A[nv][dd * 4];   // LDS broadcast
            float4 b4 = *(const float4*)&B[nv][dd * 4];
            float4 wc = WtC[dd * 16 + j];
            float4 wd = WtD[dd * 16 + j];
            a1 += a4.x*wc.x + a4.y*wc.y + a4.z*wc.z + a4.w*wc.w;
            a2 += b4.x*wd.x + b4.y*wd.y + b4.z*wd.z + b4.w*wd.w;
        }
        float tot = leaky(a1) + leaky(a2);
        float s2 = red16(tot * tot);
        float inv2 = inv_norm(s2);
        out[(size_t)v * 112 + 96 + j] = tot * inv2;  // cols 96..111
    }
}

extern "C" void kernel_launch(void* const* d_in, const int* in_sizes, int n_in,
                              void* d_out, int out_size, void* d_ws, size_t ws_size,
                              hipStream_t stream) {
    const int*   src  = (const int*)d_in[0];
    const int*   dst  = (const int*)d_in[1];
    const int*   ety  = (const int*)d_in[2];
    const float* ent  = (const float*)d_in[3];
    const float* entT = (const float*)d_in[4];
    const float* relE = (const float*)d_in[5];
    const float* relT = (const float*)d_in[6];
    const float* W1_0 = (const float*)d_in[7];
    const float* b1_0 = (const float*)d_in[8];
    const float* W2_0 = (const float*)d_in[9];
    const float* b2_0 = (const float*)d_in[10];
    const float* W1_1 = (const float*)d_in[11];
    const float* b1_1 = (const float*)d_in[12];
    const float* W2_1 = (const float*)d_in[13];
    const float* b2_1 = (const float*)d_in[14];
    float* out = (float*)d_out;

    const int E = in_sizes[0];
    const int N = in_sizes[3] / 64;
    const int nb = (N + 255) / 256;  // scan blocks (must be <= 1024)

    auto al256 = [](size_t x) { return (x + 255) & ~(size_t)255; };
    char* ws = (char*)d_ws;
    size_t offExatt = 0;
    size_t offS     = al256(offExatt + (size_t)E * 4);
    size_t offDot   = al256(offS + (size_t)N * 4);
    size_t offRow   = al256(offDot + (size_t)N * 4);
    size_t offSpk   = al256(offRow + (size_t)N * 4);
    size_t offPart  = al256(offSpk + (size_t)E * 8);
    size_t offN1    = al256(offPart + (size_t)nb * 4);
    size_t offWt    = al256(offN1 + (size_t)N * 32 * 4);
    float*  exatt    = (float*)(ws + offExatt);
    float*  sinv     = (float*)(ws + offS);
    float*  dot      = (float*)(ws + offDot);
    int*    rowptr   = (int*)(ws + offRow);
    int2*   spk2     = (int2*)(ws + offSpk);
    int*    part     = (int*)(ws + offPart);
    float*  node1raw = (float*)(ws + offN1);   // [N,32]
    float4* wt       = (float4*)(ws + offWt);  // 1280 float4 transposed weights

    // ---- CSR build + per-node dot + weight transpose ----
    hipMemsetAsync(rowptr, 0, (size_t)N * 4, stream);
    int N16 = N * 16;
    int prepWork = N16 + E + 1280;
    prep<<<(prepWork + 255) / 256, 256, 0, stream>>>(
        ent, entT, dot, dst, rowptr, N16, E, W1_0, W2_0, W1_1, W2_1, wt);
    scan_reduce<<<nb, 256, 0, stream>>>(rowptr, part, N);
    scan_part<<<1, 1024, 0, stream>>>(part, nb);
    scan_write<<<nb, 256, 0, stream>>>(rowptr, part, N);
    int blkE = (E + 255) / 256;
    scatter_edges<<<blkE, 256, 0, stream>>>(src, dst, ety, dot, rowptr, spk2, E);

    // ---- fused layer 0: attention + softmax + message + node update ----
    int nb0 = (N + 7) / 8; if (nb0 > 1024) nb0 = 1024;
    fused_l0<<<nb0, 256, 0, stream>>>(
        rowptr, spk2, ent, dot, relE, relT,
        wt, b1_0, b2_0, exatt, sinv, node1raw, out, N);

    // ---- fused layer 1: message + node update + norms ----
    int nb1 = (N + 15) / 16; if (nb1 > 2048) nb1 = 2048;
    fused_l1<<<nb1, 256, 0, stream>>>(
        rowptr, spk2, exatt, sinv, node1raw, wt,
        b1_1, b2_1, out, N);
}

// Round 12
// 207.839 us; speedup vs baseline: 1.1914x; 1.1685x over previous
//
#include <hip/hip_runtime.h>
#include <math.h>

#define EPSF 1e-12f
#define LOG2E 1.44269504f

// ---- DPP-based reductions (no DS pipe, no lane-addr calc) ----
template <int CTRL>
__device__ __forceinline__ float dppadd(float x) {
    union { float f; int i; } u, r;
    u.f = x;
    r.i = __builtin_amdgcn_update_dpp(0, u.i, CTRL, 0xF, 0xF, false);
    return x + r.f;
}
__device__ __forceinline__ float red16(float v) {
    v = dppadd<0xB1>(v); v = dppadd<0x4E>(v);
    v = dppadd<0x141>(v); v = dppadd<0x140>(v);
    return v;  // all 16 lanes hold the total
}
__device__ __forceinline__ float red8(float v) {
    v = dppadd<0xB1>(v); v = dppadd<0x4E>(v); v = dppadd<0x141>(v);
    return v;  // all 8 lanes hold the total
}
__device__ __forceinline__ float xor8add(float v) {  // combine 8-halves in 16
    return dppadd<0x128>(v);
}

// tanh(x) = 1 - 2/(e^{2x}+1) with HW exp2/rcp (exact at +/-inf limits)
__device__ __forceinline__ float fast_tanh(float x) {
    float E = __builtin_amdgcn_exp2f(x * (2.0f * LOG2E));
    return 1.0f - 2.0f * __builtin_amdgcn_rcpf(E + 1.0f);
}

// 1/max(sqrt(x), 1e-12) == rsq(max(x, 1e-24)) (monotone transform, exact)
__device__ __forceinline__ float inv_norm(float x) {
    return __builtin_amdgcn_rsqf(fmaxf(x, 1e-24f));
}

__device__ __forceinline__ float leaky(float x) {
    return x > 0.0f ? x : 0.01f * x;
}

// ---- prep: per-node dot (first N*16 threads) + degree count (next E)
//      + transposed-weight build (last 1280 items) ----
__global__ __launch_bounds__(256) void prep(
    const float* __restrict__ ent, const float* __restrict__ entT,
    float* __restrict__ dot, const int* __restrict__ dst,
    int* __restrict__ deg, int N16, int E,
    const float* __restrict__ W10, const float* __restrict__ W20,
    const float* __restrict__ W11, const float* __restrict__ W21,
    float4* __restrict__ wt) {
    int gid = blockIdx.x * 256 + threadIdx.x;
    if (gid < N16) {   // N16 is a multiple of 16, 16-lane rows never straddle
        int v = gid >> 4, lane = gid & 15;
        const float4 a = *(const float4*)(ent  + (size_t)v * 64 + lane * 4);
        const float4 b = *(const float4*)(entT + (size_t)v * 64 + lane * 4);
        float d = red16(a.x*b.x + a.y*b.y + a.z*b.z + a.w*b.w);
        if (lane == 0) dot[v] = d;
    } else if (gid < N16 + E) {
        int e = gid - N16;
        atomicAdd(&deg[dst[e]], 1);
    } else {
        int w = gid - N16 - E;  // 0..1279: build W^T float4 blocks
        if (w < 512) {
            int dd = w >> 5, j = w & 31, d4 = dd * 4;
            wt[w] = make_float4(W10[(d4+0)*32+j], W10[(d4+1)*32+j],
                                W10[(d4+2)*32+j], W10[(d4+3)*32+j]);
        } else if (w < 1024) {
            int u = w - 512, dd = u >> 5, j = u & 31, d4 = dd * 4;
            wt[w] = make_float4(W20[(d4+0)*32+j], W20[(d4+1)*32+j],
                                W20[(d4+2)*32+j], W20[(d4+3)*32+j]);
        } else if (w < 1152) {
            int u = w - 1024, dd = u >> 4, j = u & 15, d4 = dd * 4;
            wt[w] = make_float4(W11[(d4+0)*16+j], W11[(d4+1)*16+j],
                                W11[(d4+2)*16+j], W11[(d4+3)*16+j]);
        } else if (w < 1280) {
            int u = w - 1152, dd = u >> 4, j = u & 15, d4 = dd * 4;
            wt[w] = make_float4(W21[(d4+0)*16+j], W21[(d4+1)*16+j],
                                W21[(d4+2)*16+j], W21[(d4+3)*16+j]);
        }
    }
}

// ---------------- CSR scan kernels ----------------

__global__ __launch_bounds__(256) void scan_reduce(
    const int* __restrict__ deg, int* __restrict__ part, int N) {
    __shared__ int sh[256];
    int t = threadIdx.x, i = blockIdx.x * 256 + t;
    sh[t] = (i < N) ? deg[i] : 0;
    __syncthreads();
    for (int off = 128; off > 0; off >>= 1) {
        if (t < off) sh[t] += sh[t + off];
        __syncthreads();
    }
    if (t == 0) part[blockIdx.x] = sh[0];
}

__global__ __launch_bounds__(1024) void scan_part(int* __restrict__ part, int nb) {
    __shared__ int sh[1024];
    int t = threadIdx.x;
    int x = (t < nb) ? part[t] : 0;
    sh[t] = x;
    __syncthreads();
    for (int off = 1; off < 1024; off <<= 1) {
        int y = (t >= off) ? sh[t - off] : 0;
        __syncthreads();
        sh[t] += y;
        __syncthreads();
    }
    if (t < nb) part[t] = sh[t] - x;  // exclusive
}

__global__ __launch_bounds__(256) void scan_write(
    int* __restrict__ rowptr, const int* __restrict__ part, int N) {
    __shared__ int sh[256];
    int t = threadIdx.x, i = blockIdx.x * 256 + t;
    int x = (i < N) ? rowptr[i] : 0;
    sh[t] = x;
    __syncthreads();
    for (int off = 1; off < 256; off <<= 1) {
        int y = (t >= off) ? sh[t - off] : 0;
        __syncthreads();
        sh[t] += y;
        __syncthreads();
    }
    if (i < N) rowptr[i] = part[blockIdx.x] + sh[t] - x;  // exclusive scan
}

// After this, rowptr[v] = end(v); start(v) = (v ? rowptr[v-1] : 0).
// Slot payload: int2{ src | ety<<20 , bitcast(dot[src]) }.
__global__ __launch_bounds__(256) void scatter_edges(
    const int* __restrict__ src, const int* __restrict__ dst,
    const int* __restrict__ ety, const float* __restrict__ dot,
    int* __restrict__ rowptr, int2* __restrict__ spk2, int E) {
    int e = blockIdx.x * 256 + threadIdx.x;
    if (e < E) {
        int sv = src[e];
        int slot = atomicAdd(&rowptr[dst[e]], 1);
        spk2[slot] = make_int2(sv | (ety[e] << 20), __float_as_int(dot[sv]));
    }
}

// ------------- fused layer-0: att + softmax + message + bi-layer GEMV -------
// 32 lanes per dst node (8 nodes / 256-thread block): two 16-lane halves each
// walk half the node's edge list with a dual-edge pipeline + next-pair
// prefetch. DPP reductions; pre-transposed weights copied into LDS.
__global__ __launch_bounds__(256) void fused_l0(
    const int* __restrict__ rowptr, const int2* __restrict__ spk2,
    const float* __restrict__ ent, const float* __restrict__ dot,
    const float* __restrict__ relE, const float* __restrict__ relT,
    const float4* __restrict__ wt,
    const float* __restrict__ b1, const float* __restrict__ b2,
    float* __restrict__ exatt, float* __restrict__ sinv,
    float* __restrict__ node1raw, float* __restrict__ out, int N) {
    __shared__ float  al[8][64];
    __shared__ float  bl[8][64];
    __shared__ float  rT[16][64];    // rel tables (16 rels x 64)
    __shared__ float  rE[16][64];
    __shared__ float4 WtA[512];      // W1^T (pre-transposed in prep)
    __shared__ float4 WtB[512];
    int t = threadIdx.x;

    {   // stage rel tables + weights (pure coalesced float4 copies)
        int r = t >> 4, c = (t & 15) * 4;
        *(float4*)&rT[r][c] = *(const float4*)(relT + r * 64 + c);
        *(float4*)&rE[r][c] = *(const float4*)(relE + r * 64 + c);
        WtA[t]       = wt[t];
        WtA[t + 256] = wt[t + 256];
        WtB[t]       = wt[512 + t];
        WtB[t + 256] = wt[768 + t];
    }
    __syncthreads();  // the only block barrier

    int nv = t >> 5, half = (t >> 4) & 1, lane = t & 15;
    int v = blockIdx.x * 8 + nv;
    if (v >= N) return;

    int s = v ? rowptr[v - 1] : 0;
    int epos = rowptr[v];
    int deg = epos - s;
    int mid = s + ((deg + 1) >> 1);
    int hs   = half ? mid  : s;
    int hend = half ? epos : mid;

    const float4 he = *(const float4*)(ent + (size_t)v * 64 + lane * 4);
    float dh = dot[v];

    float4 macc = {0.f, 0.f, 0.f, 0.f};
    float sumex = 0.0f;

    for (int base = hs; base < hend; base += 16) {
        int rem = hend - base;
        int cnt = rem < 16 ? rem : 16;
        int2 ms = spk2[base + (lane < rem ? lane : rem - 1)];  // coalesced 8B
        float myex = 0.0f;

        int pk0 = __shfl(ms.x, 0, 16);
        int pk1 = __shfl(ms.x, cnt > 1 ? 1 : 0, 16);
        float sd0 = __int_as_float(__shfl(ms.y, 0, 16));
        float sd1 = __int_as_float(__shfl(ms.y, cnt > 1 ? 1 : 0, 16));
        float4 te0 = *(const float4*)(ent + (size_t)(pk0 & 0xFFFFF) * 64 + lane * 4);
        float4 te1 = *(const float4*)(ent + (size_t)(pk1 & 0xFFFFF) * 64 + lane * 4);

        for (int k = 0; k < cnt; k += 2) {
            float4 ta = te0, tb = te1;
            float  sa = sd0, sb = sd1;
            int rva = (pk0 >> 20) & 15;
            int rvb = (pk1 >> 20) & 15;
            bool hasb = (k + 1) < cnt;

            if (k + 2 < cnt) {  // prefetch next pair while computing this one
                int i2 = k + 2, i3 = (k + 3 < cnt) ? (k + 3) : (k + 2);
                pk0 = __shfl(ms.x, i2, 16);
                pk1 = __shfl(ms.x, i3, 16);
                sd0 = __int_as_float(__shfl(ms.y, i2, 16));
                sd1 = __int_as_float(__shfl(ms.y, i3, 16));
                te0 = *(const float4*)(ent + (size_t)(pk0 & 0xFFFFF) * 64 + lane * 4);
                te1 = *(const float4*)(ent + (size_t)(pk1 & 0xFFFFF) * 64 + lane * 4);
            }

            const float4 rpa = *(const float4*)&rT[rva][lane * 4];
            const float4 rea = *(const float4*)&rE[rva][lane * 4];
            const float4 rpb = *(const float4*)&rT[rvb][lane * 4];
            const float4 reb = *(const float4*)&rE[rvb][lane * 4];

            float4 mta, mha, mtb, mhb;
            mta.x = ta.x + sa * rpa.x; mta.y = ta.y + sa * rpa.y;
            mta.z = ta.z + sa * rpa.z; mta.w = ta.w + sa * rpa.w;
            mha.x = he.x + dh * rpa.x; mha.y = he.y + dh * rpa.y;
            mha.z = he.z + dh * rpa.z; mha.w = he.w + dh * rpa.w;
            mtb.x = tb.x + sb * rpb.x; mtb.y = tb.y + sb * rpb.y;
            mtb.z = tb.z + sb * rpb.z; mtb.w = tb.w + sb * rpb.w;
            mhb.x = he.x + dh * rpb.x; mhb.y = he.y + dh * rpb.y;
            mhb.z = he.z + dh * rpb.z; mhb.w = he.w + dh * rpb.w;

            float ssta = red16(mta.x*mta.x + mta.y*mta.y + mta.z*mta.z + mta.w*mta.w);
            float ssha = red16(mha.x*mha.x + mha.y*mha.y + mha.z*mha.z + mha.w*mha.w);
            float sstb = red16(mtb.x*mtb.x + mtb.y*mtb.y + mtb.z*mtb.z + mtb.w*mtb.w);
            float sshb = red16(mhb.x*mhb.x + mhb.y*mhb.y + mhb.z*mhb.z + mhb.w*mhb.w);
            float ita = inv_norm(ssta), iha = inv_norm(ssha);
            float itb = inv_norm(sstb), ihb = inv_norm(sshb);

            float txa = fast_tanh(mha.x * iha + rea.x);
            float tya = fast_tanh(mha.y * iha + rea.y);
            float tza = fast_tanh(mha.z * iha + rea.z);
            float twa = fast_tanh(mha.w * iha + rea.w);
            float txb = fast_tanh(mhb.x * ihb + reb.x);
            float tyb = fast_tanh(mhb.y * ihb + reb.y);
            float tzb = fast_tanh(mhb.z * ihb + reb.z);
            float twb = fast_tanh(mhb.w * ihb + reb.w);

            float atta = ita * red16(mta.x*txa + mta.y*tya + mta.z*tza + mta.w*twa);
            float attb = itb * red16(mtb.x*txb + mtb.y*tyb + mtb.z*tzb + mtb.w*twb);

            // softmax shift-invariant; |att| <= 8 so exp is safe without max-sub
            float exa  = __builtin_amdgcn_exp2f(atta * LOG2E);
            float exbR = __builtin_amdgcn_exp2f(attb * LOG2E);
            float exb  = hasb ? exbR : 0.0f;

            // lane k captures its edge's raw ex; stored coalesced per chunk
            myex = (lane == k) ? exa : myex;
            myex = (lane == k + 1) ? exbR : myex;

            sumex += exa + exb;
            macc.x += exa * ta.x + exb * tb.x;
            macc.y += exa * ta.y + exb * tb.y;
            macc.z += exa * ta.z + exb * tb.z;
            macc.w += exa * ta.w + exb * tb.w;
        }
        if (lane < cnt) exatt[base + lane] = myex;
    }

    // combine the two halves of this node (width-32 xor-by-16)
    sumex  += __shfl_xor(sumex,  16, 32);
    macc.x += __shfl_xor(macc.x, 16, 32);
    macc.y += __shfl_xor(macc.y, 16, 32);
    macc.z += __shfl_xor(macc.z, 16, 32);
    macc.w += __shfl_xor(macc.w, 16, 32);

    float inv = 1.0f / fmaxf(sumex, EPSF);
    if ((t & 31) == 0) sinv[v] = inv;
    macc.x *= inv; macc.y *= inv; macc.z *= inv; macc.w *= inv;

    if (!half) {
        // out cols 0..63 = ent_embed
        *(float4*)(out + (size_t)v * 112 + lane * 4) = he;
        float4 av, bv;
        av.x = he.x + macc.x; av.y = he.y + macc.y;
        av.z = he.z + macc.z; av.w = he.w + macc.w;
        bv.x = he.x * macc.x; bv.y = he.y * macc.y;
        bv.z = he.z * macc.z; bv.w = he.w * macc.w;
        *(float4*)&al[nv][lane * 4] = av;
        *(float4*)&bl[nv][lane * 4] = bv;
    }
    // no __syncthreads: writers and readers are the same wave (program order)

    int j = t & 31;
    float acc1 = b1[j], acc2 = b2[j];
    #pragma unroll
    for (int dd = 0; dd < 16; ++dd) {
        float4 a4 = *(const float4*)&al[nv][dd * 4];   // LDS broadcast read
        float4 b4 = *(const float4*)&bl[nv][dd * 4];
        float4 wa = WtA[dd * 32 + j];                  // coalesced b128
        float4 wb = WtB[dd * 32 + j];
        acc1 += a4.x*wa.x + a4.y*wa.y + a4.z*wa.z + a4.w*wa.w;
        acc2 += b4.x*wb.x + b4.y*wb.y + b4.z*wb.z + b4.w*wb.w;
    }
    node1raw[(size_t)v * 32 + j] = leaky(acc1) + leaky(acc2);
}

// ------------- fused layer-1: message gather + bi-layer GEMV + norms --------
// 16 lanes per node (16 nodes / block): two 8-lane halves, dual-edge pipeline.
__global__ __launch_bounds__(256) void fused_l1(
    const int* __restrict__ rowptr, const int2* __restrict__ spk2,
    const float* __restrict__ exatt, const float* __restrict__ sinv,
    const float* __restrict__ node1raw, const float4* __restrict__ wt,
    const float* __restrict__ b1, const float* __restrict__ b2,
    float* __restrict__ out, int N) {
    __shared__ float  A[16][32];
    __shared__ float  B[16][32];
    __shared__ float4 WtC[128];  // W1^T (pre-transposed in prep)
    __shared__ float4 WtD[128];
    int t = threadIdx.x;

    {   // stage weights (pure coalesced float4 copies)
        if (t < 128) WtC[t] = wt[1024 + t];
        else WtD[t - 128] = wt[1024 + t];
    }
    __syncthreads();

    int nv = t >> 4, half = (t >> 3) & 1, lane = t & 7;
    int v = blockIdx.x * 16 + nv;
    if (v >= N) return;

    int s = v ? rowptr[v - 1] : 0;
    int epos = rowptr[v];
    int deg = epos - s;
    int mid = s + ((deg + 1) >> 1);
    int hs   = half ? mid  : s;
    int hend = half ? epos : mid;

    float4 n = *(const float4*)(node1raw + (size_t)v * 32 + lane * 4);
    float4 acc = {0.f, 0.f, 0.f, 0.f};

    for (int base = hs; base < hend; base += 8) {
        int rem = hend - base;
        int cnt = rem < 8 ? rem : 8;
        int idx = base + (lane < rem ? lane : rem - 1);
        int   mypk = spk2[idx].x;
        float myex = exatt[idx];

        int pk0 = __shfl(mypk, 0, 8);
        int pk1 = __shfl(mypk, cnt > 1 ? 1 : 0, 8);
        float4 x0 = *(const float4*)(node1raw + (size_t)(pk0 & 0xFFFFF) * 32 + lane * 4);
        float4 x1 = *(const float4*)(node1raw + (size_t)(pk1 & 0xFFFFF) * 32 + lane * 4);

        for (int k = 0; k < cnt; k += 2) {
            float4 xa = x0, xb = x1;
            float aa = __shfl(myex, k, 8);
            float ab = __shfl(myex, (k + 1 < cnt) ? (k + 1) : k, 8);
            if (!((k + 1) < cnt)) ab = 0.0f;

            if (k + 2 < cnt) {
                pk0 = __shfl(mypk, k + 2, 8);
                pk1 = __shfl(mypk, (k + 3 < cnt) ? (k + 3) : (k + 2), 8);
                x0 = *(const float4*)(node1raw + (size_t)(pk0 & 0xFFFFF) * 32 + lane * 4);
                x1 = *(const float4*)(node1raw + (size_t)(pk1 & 0xFFFFF) * 32 + lane * 4);
            }
            acc.x += aa * xa.x + ab * xb.x;
            acc.y += aa * xa.y + ab * xb.y;
            acc.z += aa * xa.z + ab * xb.z;
            acc.w += aa * xa.w + ab * xb.w;
        }
    }
    // combine halves (lane^8 within 16, via DPP row_ror:8)
    acc.x = xor8add(acc.x);
    acc.y = xor8add(acc.y);
    acc.z = xor8add(acc.z);
    acc.w = xor8add(acc.w);

    float inv = sinv[v];
    acc.x *= inv; acc.y *= inv; acc.z *= inv; acc.w *= inv;

    float ss = red8(n.x*n.x + n.y*n.y + n.z*n.z + n.w*n.w);
    float inv1 = inv_norm(ss);

    if (!half) {
        float4 nn = {n.x*inv1, n.y*inv1, n.z*inv1, n.w*inv1};
        *(float4*)(out + (size_t)v * 112 + 64 + lane * 4) = nn;
        float4 av = {n.x + acc.x, n.y + acc.y, n.z + acc.z, n.w + acc.w};
        float4 bv = {n.x * acc.x, n.y * acc.y, n.z * acc.z, n.w * acc.w};
        *(float4*)&A[nv][lane * 4] = av;
        *(float4*)&B[nv][lane * 4] = bv;
    }
    // no __syncthreads: writers and readers are the same wave (program order)

    int j = t & 15;
    float a1 = b1[j], a2 = b2[j];
    #pragma unroll
    for (int dd = 0; dd < 8; ++dd) {
        float4 a4 = *(const float4*)&A[nv][dd * 4];   // LDS broadcast read
        float4 b4 = *(const float4*)&B[nv][dd * 4];
        float4 wc = WtC[dd * 16 + j];
        float4 wd = WtD[dd * 16 + j];
        a1 += a4.x*wc.x + a4.y*wc.y + a4.z*wc.z + a4.w*wc.w;
        a2 += b4.x*wd.x + b4.y*wd.y + b4.z*wd.z + b4.w*wd.w;
    }
    float tot = leaky(a1) + leaky(a2);
    float s2 = red16(tot * tot);
    float inv2 = inv_norm(s2);
    out[(size_t)v * 112 + 96 + j] = tot * inv2;  // cols 96..111
}

extern "C" void kernel_launch(void* const* d_in, const int* in_sizes, int n_in,
                              void* d_out, int out_size, void* d_ws, size_t ws_size,
                              hipStream_t stream) {
    const int*   src  = (const int*)d_in[0];
    const int*   dst  = (const int*)d_in[1];
    const int*   ety  = (const int*)d_in[2];
    const float* ent  = (const float*)d_in[3];
    const float* entT = (const float*)d_in[4];
    const float* relE = (const float*)d_in[5];
    const float* relT = (const float*)d_in[6];
    const float* W1_0 = (const float*)d_in[7];
    const float* b1_0 = (const float*)d_in[8];
    const float* W2_0 = (const float*)d_in[9];
    const float* b2_0 = (const float*)d_in[10];
    const float* W1_1 = (const float*)d_in[11];
    const float* b1_1 = (const float*)d_in[12];
    const float* W2_1 = (const float*)d_in[13];
    const float* b2_1 = (const float*)d_in[14];
    float* out = (float*)d_out;

    const int E = in_sizes[0];
    const int N = in_sizes[3] / 64;
    const int nb = (N + 255) / 256;  // scan blocks (must be <= 1024)

    auto al256 = [](size_t x) { return (x + 255) & ~(size_t)255; };
    char* ws = (char*)d_ws;
    size_t offExatt = 0;
    size_t offS     = al256(offExatt + (size_t)E * 4);
    size_t offDot   = al256(offS + (size_t)N * 4);
    size_t offRow   = al256(offDot + (size_t)N * 4);
    size_t offSpk   = al256(offRow + (size_t)N * 4);
    size_t offPart  = al256(offSpk + (size_t)E * 8);
    size_t offN1    = al256(offPart + (size_t)nb * 4);
    size_t offWt    = al256(offN1 + (size_t)N * 32 * 4);
    float*  exatt    = (float*)(ws + offExatt);
    float*  sinv     = (float*)(ws + offS);
    float*  dot      = (float*)(ws + offDot);
    int*    rowptr   = (int*)(ws + offRow);
    int2*   spk2     = (int2*)(ws + offSpk);
    int*    part     = (int*)(ws + offPart);
    float*  node1raw = (float*)(ws + offN1);   // [N,32]
    float4* wt       = (float4*)(ws + offWt);  // 1280 float4 transposed weights

    // ---- CSR build + per-node dot + weight transpose ----
    hipMemsetAsync(rowptr, 0, (size_t)N * 4, stream);
    int N16 = N * 16;
    int prepWork = N16 + E + 1280;
    prep<<<(prepWork + 255) / 256, 256, 0, stream>>>(
        ent, entT, dot, dst, rowptr, N16, E, W1_0, W2_0, W1_1, W2_1, wt);
    scan_reduce<<<nb, 256, 0, stream>>>(rowptr, part, N);
    scan_part<<<1, 1024, 0, stream>>>(part, nb);
    scan_write<<<nb, 256, 0, stream>>>(rowptr, part, N);
    int blkE = (E + 255) / 256;
    scatter_edges<<<blkE, 256, 0, stream>>>(src, dst, ety, dot, rowptr, spk2, E);

    // ---- fused layer 0: attention + softmax + message + node update ----
    fused_l0<<<(N + 7) / 8, 256, 0, stream>>>(
        rowptr, spk2, ent, dot, relE, relT,
        wt, b1_0, b2_0, exatt, sinv, node1raw, out, N);

    // ---- fused layer 1: message + node update + norms ----
    fused_l1<<<(N + 15) / 16, 256, 0, stream>>>(
        rowptr, spk2, exatt, sinv, node1raw, wt,
        b1_1, b2_1, out, N);
}